// Round 7
// baseline (310.788 us; speedup 1.0000x reference)
//
#include <hip/hip_runtime.h>
#include <hip/hip_cooperative_groups.h>
#include <cmath>

namespace cg = cooperative_groups;
#define DI __device__ __forceinline__

constexpr int BS = 32;
constexpr int NS = 65536;
constexpr int NF = 128;
constexpr int TB = 256;             // threads per block
constexpr int S  = 16;              // samples per thread (2 groups of 8)
constexpr int G  = 8;
constexpr int SAMP = TB * S;        // 4096 samples per chunk
constexpr int NC = NS / SAMP;       // 16 chunks per batch
constexpr int GRID = BS * NC;       // 512 blocks
constexpr int NFR = 10;             // frames staged per chunk
constexpr size_t U = (size_t)BS * NS;
constexpr double PI_D = 3.14159265358979323846;
constexpr float STAB = 0.999f;
constexpr float CPOS = 127.0f / 65535.0f;

// Affine map on IIR state s=(y[t-1],y[t-2]):  s' = M*s + v.
struct M6 { float a, b, c, d, u, v; };

DI M6 comp(const M6& R, const M6& L) {   // apply L first, then R
    M6 o;
    o.a = fmaf(R.a, L.a, R.b * L.c);
    o.b = fmaf(R.a, L.b, R.b * L.d);
    o.c = fmaf(R.c, L.a, R.d * L.c);
    o.d = fmaf(R.c, L.b, R.d * L.d);
    o.u = fmaf(R.a, L.u, fmaf(R.b, L.v, R.u));
    o.v = fmaf(R.c, L.u, fmaf(R.d, L.v, R.v));
    return o;
}

DI void stepL(M6& A, float a1, float a2, float x) {  // prepend later-in-time step
    float na = fmaf(-a1, A.a, -a2 * A.c);
    float nb = fmaf(-a1, A.b, -a2 * A.d);
    float nu = fmaf(-a1, A.u, fmaf(-a2, A.v, x));
    A.c = A.a; A.d = A.b; A.v = A.u;
    A.a = na;  A.b = nb;  A.u = nu;
}

template <int W>
DI void wave_scan6(M6& s, int lane) {    // inclusive over W lanes (lane order = time)
    #pragma unroll
    for (int d = 1; d < W; d <<= 1) {
        M6 o;
        o.a = __shfl_up(s.a, d, 64); o.b = __shfl_up(s.b, d, 64);
        o.c = __shfl_up(s.c, d, 64); o.d = __shfl_up(s.d, d, 64);
        o.u = __shfl_up(s.u, d, 64); o.v = __shfl_up(s.v, d, 64);
        M6 t = comp(s, o);
        bool p = lane >= d;
        s.a = p ? t.a : s.a; s.b = p ? t.b : s.b; s.c = p ? t.c : s.c;
        s.d = p ? t.d : s.d; s.u = p ? t.u : s.u; s.v = p ? t.v : s.v;
    }
}

DI M6 ld6(const float* p) { M6 m; m.a=p[0]; m.b=p[1]; m.c=p[2]; m.d=p[3]; m.u=p[4]; m.v=p[5]; return m; }
DI void st6(float* p, const M6& m) { p[0]=m.a; p[1]=m.b; p[2]=m.c; p[3]=m.d; p[4]=m.u; p[5]=m.v; }

DI float fast_tanh(float x) {            // exact at saturation (inf-safe)
    float e = __expf(2.0f * x);
    return 1.0f - 2.0f / (e + 1.0f);
}

DI void stage_frames(const float* __restrict__ logits, int b, int F, int tid,
                     float (*sfa)[2], float (*sfb)[3]) {
    if (tid < NFR) {
        int fidx = F + tid; if (fidx > 127) fidx = 127;
        const float* L = logits + (size_t)(b * NF + fidx) * 5;
        float a1 = 2.0f * tanhf(L[0]) * STAB;
        float aa = fabsf(a1);
        float a2 = ((2.0f - aa) * tanhf(L[1]) * STAB + aa) * 0.5f;
        sfa[tid][0] = a1; sfa[tid][1] = a2;
        sfb[tid][0] = L[2]; sfb[tid][1] = L[3]; sfb[tid][2] = L[4];
    }
}

DI void interp_at(int t, int F, const float (*sfa)[2], const float (*sfb)[3],
                  float& a1, float& a2, float& b0, float& b1, float& b2) {
    float pos = (float)t * CPOS;                 // monotone; floor(pos) >= F
    int i0 = (int)pos;
    int i1 = (i0 + 1 > 127) ? 127 : i0 + 1;
    float fr = pos - (float)i0, w0 = 1.0f - fr;
    int l0 = i0 - F, l1 = i1 - F;
    a1 = sfa[l0][0] * w0 + sfa[l1][0] * fr;
    a2 = sfa[l0][1] * w0 + sfa[l1][1] * fr;
    b0 = sfb[l0][0] * w0 + sfb[l1][0] * fr;
    b1 = sfb[l0][1] * w0 + sfb[l1][1] * fr;
    b2 = sfb[l0][2] * w0 + sfb[l1][2] * fr;
}

// Block scan over per-thread aggregates; returns EXCLUSIVE prefix for this
// thread; if publish!=nullptr, tid TB-1 stores the block total there.
// Contains one __syncthreads.
DI M6 block_scan_E(M6 A, float (*wt)[6], int tid, float* publish) {
    const int lane = tid & 63, w = tid >> 6;
    wave_scan6<64>(A, lane);
    if (lane == 63) st6(wt[w], A);
    __syncthreads();
    M6 P; P.a = 1.f; P.b = 0.f; P.c = 0.f; P.d = 1.f; P.u = 0.f; P.v = 0.f;
    for (int i = 0; i < w; i++) P = comp(ld6(wt[i]), P);
    if (publish && tid == TB - 1) st6(publish, comp(A, P));
    M6 prev;
    prev.a = __shfl_up(A.a, 1, 64); prev.b = __shfl_up(A.b, 1, 64);
    prev.c = __shfl_up(A.c, 1, 64); prev.d = __shfl_up(A.d, 1, 64);
    prev.u = __shfl_up(A.u, 1, 64); prev.v = __shfl_up(A.v, 1, 64);
    return (lane == 0) ? P : comp(prev, P);
}

// wave 0 scans this batch's NC chunk summaries into sv (state after chunk i).
DI void cross_scan(const float* __restrict__ ws_chunk, int b, int tid,
                   float (*sv)[2]) {
    if (tid < 64) {
        M6 cs;
        if (tid < NC) cs = ld6(ws_chunk + ((size_t)b * NC + tid) * 6);
        else { cs.a = 1.f; cs.b = 0.f; cs.c = 0.f; cs.d = 1.f; cs.u = 0.f; cs.v = 0.f; }
        wave_scan6<NC>(cs, tid);
        if (tid < NC) { sv[tid][0] = cs.u; sv[tid][1] = cs.v; }
    }
}

// ---- phase 1: osc + env + coeff planes + per-thread aggregate + block scan --
DI M6 dev_phase1(int b, int c, int tid,
    const float* __restrict__ f0_hz, const float* __restrict__ note_dur,
    const float* __restrict__ phase, const float* __restrict__ logits,
    const float* __restrict__ osc_shape, const float* __restrict__ osc_gain,
    const float* __restrict__ alpha,
    float* __restrict__ ws_chunk, float* __restrict__ out,
    float (*sfa)[2], float (*sfb)[3], float (*wt)[6], float* x16) {
    const int t0 = c * SAMP + tid * S;
    const size_t g0 = (size_t)b * NS + t0;
    const int F = (int)((float)(c * SAMP) * CPOS);

    stage_frames(logits, b, F, tid, sfa, sfb);

    const float f0 = f0_hz[b], ph = phase[b], sh = osc_shape[b];
    const float gn = osc_gain[b], dur = note_dur[b], al = alpha[b];
    const double inc = (double)f0 / 48000.0;
    const float partials = 12000.0f / (f0 * __log10f(f0));
    const double cum0 = (double)(t0 + 1) * inc;
    const double uu0 = cum0 - 2.0 * floor(cum0 * 0.5);            // mod 2
    const float theta0 = (float)(PI_D * uu0 + 0.5 * (double)ph);  // arg/2
    const float dth = (float)(PI_D * inc);

    __syncthreads();   // frame staging visible

    M6 A;
    #pragma unroll
    for (int h = 0; h < 2; h++) {
        float xv[G], ev[G], a1s[G], a2s[G], b0s[G], b1s[G], b2s[G];
        #pragma unroll
        for (int k = 0; k < G; k++) {
            int idx = h * G + k, t = t0 + idx;
            float theta = theta0 + (float)idx * dth;
            float sn, cs;
            __sincosf(theta, &sn, &cs);
            float sq = fast_tanh(1.57079632679f * partials * (2.0f * sn * cs));
            float dry0 = (1.0f - 0.5f * sh) * sq * (1.0f + sh * cs);
            float tsec = (float)t * (1.0f / 48000.0f);
            float env = 0.0f;
            if (tsec <= dur) {
                float ramp = 1.0f - tsec / dur;
                ramp = ramp < 0.001f ? 0.001f : (ramp > 1.0f ? 1.0f : ramp);
                env = __expf(al * __logf(ramp));
            }
            ev[k] = env;
            float x = dry0 * gn * env;
            xv[k] = x; x16[idx] = x;
            float a1, a2, b0, b1, b2;
            interp_at(t, F, sfa, sfb, a1, a2, b0, b1, b2);
            a1s[k] = a1; a2s[k] = a2; b0s[k] = b0; b1s[k] = b1; b2s[k] = b2;
            if (h == 0 && k == 0) { A.a = -a1; A.b = -a2; A.c = 1.f; A.d = 0.f; A.u = x; A.v = 0.f; }
            else stepL(A, a1, a2, x);
        }
        const size_t gh = g0 + h * G;
        *(float4*)&out[gh]             = make_float4(xv[0], xv[1], xv[2], xv[3]);
        *(float4*)&out[gh + 4]         = make_float4(xv[4], xv[5], xv[6], xv[7]);
        *(float4*)&out[2 * U + gh]     = make_float4(ev[0], ev[1], ev[2], ev[3]);
        *(float4*)&out[2 * U + gh + 4] = make_float4(ev[4], ev[5], ev[6], ev[7]);
        float* a3 = out + 4 * U + gh * 3;
        *(float4*)&a3[0]  = make_float4(1.0f, a1s[0], a2s[0], 1.0f);
        *(float4*)&a3[4]  = make_float4(a1s[1], a2s[1], 1.0f, a1s[2]);
        *(float4*)&a3[8]  = make_float4(a2s[2], 1.0f, a1s[3], a2s[3]);
        *(float4*)&a3[12] = make_float4(1.0f, a1s[4], a2s[4], 1.0f);
        *(float4*)&a3[16] = make_float4(a1s[5], a2s[5], 1.0f, a1s[6]);
        *(float4*)&a3[20] = make_float4(a2s[6], 1.0f, a1s[7], a2s[7]);
        float* bc = out + 7 * U + gh * 3;
        *(float4*)&bc[0]  = make_float4(b0s[0], b1s[0], b2s[0], b0s[1]);
        *(float4*)&bc[4]  = make_float4(b1s[1], b2s[1], b0s[2], b1s[2]);
        *(float4*)&bc[8]  = make_float4(b2s[2], b0s[3], b1s[3], b2s[3]);
        *(float4*)&bc[12] = make_float4(b0s[4], b1s[4], b2s[4], b0s[5]);
        *(float4*)&bc[16] = make_float4(b1s[5], b2s[5], b0s[6], b1s[6]);
        *(float4*)&bc[20] = make_float4(b2s[6], b0s[7], b1s[7], b2s[7]);
    }
    return block_scan_E(A, wt, tid, ws_chunk + ((size_t)b * NC + c) * 6);
}

// ---- phase 2: replay with true state + FIR + tanh + stores ------------------
DI void dev_phase2(int b, int c, int tid, const float* x16, M6 E,
                   float s0, float s1, const float (*sfa)[2],
                   const float (*sfb)[3], float dg, float* __restrict__ out) {
    const int t0 = c * SAMP + tid * S;
    const size_t g0 = (size_t)b * NS + t0;
    const int F = (int)((float)(c * SAMP) * CPOS);
    float y1 = fmaf(E.a, s0, fmaf(E.b, s1, E.u));   // y[t0-1]
    float y2 = fmaf(E.c, s0, fmaf(E.d, s1, E.v));   // y[t0-2]
    #pragma unroll
    for (int h = 0; h < 2; h++) {
        float yv[G], yabv[G], wetv[G];
        #pragma unroll
        for (int k = 0; k < G; k++) {
            int idx = h * G + k, t = t0 + idx;
            float a1, a2, b0, b1, b2;
            interp_at(t, F, sfa, sfb, a1, a2, b0, b1, b2);
            float yn = fmaf(-a1, y1, fmaf(-a2, y2, x16[idx]));
            float yab = b0 * yn + b1 * y1 + b2 * y2;
            yv[k] = yn; yabv[k] = yab; wetv[k] = fast_tanh(yab * dg);
            y2 = y1; y1 = yn;
        }
        const size_t gh = g0 + h * G;
        *(float4*)&out[U + gh]          = make_float4(wetv[0], wetv[1], wetv[2], wetv[3]);
        *(float4*)&out[U + gh + 4]      = make_float4(wetv[4], wetv[5], wetv[6], wetv[7]);
        *(float4*)&out[3 * U + gh]      = make_float4(yabv[0], yabv[1], yabv[2], yabv[3]);
        *(float4*)&out[3 * U + gh + 4]  = make_float4(yabv[4], yabv[5], yabv[6], yabv[7]);
        *(float4*)&out[10 * U + gh]     = make_float4(yv[0], yv[1], yv[2], yv[3]);
        *(float4*)&out[10 * U + gh + 4] = make_float4(yv[4], yv[5], yv[6], yv[7]);
    }
}

// ---------------- fused cooperative kernel -----------------------------------
__global__ __launch_bounds__(TB, 4) void k_fused(
    const float* __restrict__ f0_hz, const float* __restrict__ note_dur,
    const float* __restrict__ phase, const float* __restrict__ logits,
    const float* __restrict__ osc_shape, const float* __restrict__ osc_gain,
    const float* __restrict__ dist_gain, const float* __restrict__ alpha,
    float* __restrict__ ws_chunk, float* __restrict__ out) {
    __shared__ float sfa[NFR][2], sfb[NFR][3], wt[4][6], sv[NC][2];
    const int bid = blockIdx.x, b = bid / NC, c = bid % NC, tid = threadIdx.x;
    float x16[S];
    M6 E = dev_phase1(b, c, tid, f0_hz, note_dur, phase, logits, osc_shape,
                      osc_gain, alpha, ws_chunk, out, sfa, sfb, wt, x16);
    __threadfence();
    cg::this_grid().sync();
    cross_scan(ws_chunk, b, tid, sv);
    __syncthreads();
    const float s0 = c ? sv[c - 1][0] : 0.0f;
    const float s1 = c ? sv[c - 1][1] : 0.0f;
    dev_phase2(b, c, tid, x16, E, s0, s1, sfa, sfb, dist_gain[b], out);
}

// ---------------- fallback pair (no cooperative launch needed) ---------------
__global__ __launch_bounds__(TB) void k_p1(
    const float* __restrict__ f0_hz, const float* __restrict__ note_dur,
    const float* __restrict__ phase, const float* __restrict__ logits,
    const float* __restrict__ osc_shape, const float* __restrict__ osc_gain,
    const float* __restrict__ alpha,
    float* __restrict__ ws_chunk, float* __restrict__ out) {
    __shared__ float sfa[NFR][2], sfb[NFR][3], wt[4][6];
    const int bid = blockIdx.x, b = bid / NC, c = bid % NC, tid = threadIdx.x;
    float x16[S];
    (void)dev_phase1(b, c, tid, f0_hz, note_dur, phase, logits, osc_shape,
                     osc_gain, alpha, ws_chunk, out, sfa, sfb, wt, x16);
}

__global__ __launch_bounds__(TB) void k_p2(
    const float* __restrict__ logits, const float* __restrict__ dist_gain,
    const float* __restrict__ ws_chunk, float* __restrict__ out) {
    __shared__ float sfa[NFR][2], sfb[NFR][3], wt[4][6], sv[NC][2];
    const int bid = blockIdx.x, b = bid / NC, c = bid % NC, tid = threadIdx.x;
    const int t0 = c * SAMP + tid * S;
    const size_t g0 = (size_t)b * NS + t0;
    const int F = (int)((float)(c * SAMP) * CPOS);

    stage_frames(logits, b, F, tid, sfa, sfb);
    cross_scan(ws_chunk, b, tid, sv);

    float x16[S];
    #pragma unroll
    for (int q = 0; q < S / 4; q++) {
        float4 v = *(const float4*)&out[g0 + q * 4];     // dry plane (k_p1 output)
        x16[q * 4 + 0] = v.x; x16[q * 4 + 1] = v.y;
        x16[q * 4 + 2] = v.z; x16[q * 4 + 3] = v.w;
    }
    __syncthreads();   // staging + sv visible

    M6 A;
    #pragma unroll
    for (int k = 0; k < S; k++) {
        float a1, a2, b0, b1, b2;
        interp_at(t0 + k, F, sfa, sfb, a1, a2, b0, b1, b2);
        if (k == 0) { A.a = -a1; A.b = -a2; A.c = 1.f; A.d = 0.f; A.u = x16[0]; A.v = 0.f; }
        else stepL(A, a1, a2, x16[k]);
    }
    M6 E = block_scan_E(A, wt, tid, nullptr);
    const float s0 = c ? sv[c - 1][0] : 0.0f;
    const float s1 = c ? sv[c - 1][1] : 0.0f;
    dev_phase2(b, c, tid, x16, E, s0, s1, sfa, sfb, dist_gain[b], out);
}

extern "C" void kernel_launch(void* const* d_in, const int* in_sizes, int n_in,
                              void* d_out, int out_size, void* d_ws, size_t ws_size,
                              hipStream_t stream) {
    const float* f0   = (const float*)d_in[0];
    const float* dur  = (const float*)d_in[1];
    const float* ph   = (const float*)d_in[2];
    const float* lg   = (const float*)d_in[3];
    const float* shp  = (const float*)d_in[4];
    const float* gn   = (const float*)d_in[5];
    const float* dist = (const float*)d_in[6];
    const float* alp  = (const float*)d_in[7];
    float* out = (float*)d_out;
    float* ws_chunk = (float*)d_ws;            // GRID*6 f32 = 12 KB

    // Gate cooperative launch on actual capacity (R6 failed silently at the
    // capacity boundary); fall back to the proven 2-kernel path otherwise.
    int dev = 0, numCU = 0, maxb = 0;
    (void)hipGetDevice(&dev);
    (void)hipDeviceGetAttribute(&numCU, hipDeviceAttributeMultiprocessorCount, dev);
    hipError_t qe = hipOccupancyMaxActiveBlocksPerMultiprocessor(
        &maxb, (const void*)k_fused, TB, 0);
    bool ok = (qe == hipSuccess) && numCU > 0 && (long)maxb * numCU >= GRID;
    if (ok) {
        void* args[] = {(void*)&f0, (void*)&dur, (void*)&ph, (void*)&lg,
                        (void*)&shp, (void*)&gn, (void*)&dist, (void*)&alp,
                        (void*)&ws_chunk, (void*)&out};
        if (hipLaunchCooperativeKernel((const void*)k_fused, dim3(GRID), dim3(TB),
                                       args, 0, stream) != hipSuccess)
            ok = false;
    }
    if (!ok) {
        k_p1<<<GRID, TB, 0, stream>>>(f0, dur, ph, lg, shp, gn, alp, ws_chunk, out);
        k_p2<<<GRID, TB, 0, stream>>>(lg, dist, ws_chunk, out);
    }
}

// Round 8
// 141.051 us; speedup vs baseline: 2.2034x; 2.2034x over previous
//
#include <hip/hip_runtime.h>
#include <cmath>

#define DI __device__ __forceinline__

constexpr int BS = 32;
constexpr int NS = 65536;
constexpr int NF = 128;
constexpr int TB = 256;             // threads per block
constexpr int S  = 8;               // samples per thread (2 groups of 4)
constexpr int G  = 4;
constexpr int SAMP = TB * S;        // 2048 samples per chunk
constexpr int NC = NS / SAMP;       // 32 chunks per batch
constexpr int GRID = BS * NC;       // 1024 blocks
constexpr int NFR = 6;              // frames staged per chunk (2048 smpl -> <=5)
constexpr size_t U = (size_t)BS * NS;
constexpr double PI_D = 3.14159265358979323846;
constexpr float STAB = 0.999f;
constexpr float CPOS = 127.0f / 65535.0f;

// Affine map on IIR state s=(y[t-1],y[t-2]):  s' = M*s + v.
struct M6 { float a, b, c, d, u, v; };

DI M6 comp(const M6& R, const M6& L) {   // apply L first, then R
    M6 o;
    o.a = fmaf(R.a, L.a, R.b * L.c);
    o.b = fmaf(R.a, L.b, R.b * L.d);
    o.c = fmaf(R.c, L.a, R.d * L.c);
    o.d = fmaf(R.c, L.b, R.d * L.d);
    o.u = fmaf(R.a, L.u, fmaf(R.b, L.v, R.u));
    o.v = fmaf(R.c, L.u, fmaf(R.d, L.v, R.v));
    return o;
}

DI void stepL(M6& A, float a1, float a2, float x) {  // prepend later-in-time step
    float na = fmaf(-a1, A.a, -a2 * A.c);
    float nb = fmaf(-a1, A.b, -a2 * A.d);
    float nu = fmaf(-a1, A.u, fmaf(-a2, A.v, x));
    A.c = A.a; A.d = A.b; A.v = A.u;
    A.a = na;  A.b = nb;  A.u = nu;
}

template <int W>
DI void wave_scan6(M6& s, int lane) {    // inclusive over W lanes (lane order = time)
    #pragma unroll
    for (int d = 1; d < W; d <<= 1) {
        M6 o;
        o.a = __shfl_up(s.a, d, 64); o.b = __shfl_up(s.b, d, 64);
        o.c = __shfl_up(s.c, d, 64); o.d = __shfl_up(s.d, d, 64);
        o.u = __shfl_up(s.u, d, 64); o.v = __shfl_up(s.v, d, 64);
        M6 t = comp(s, o);
        bool p = lane >= d;
        s.a = p ? t.a : s.a; s.b = p ? t.b : s.b; s.c = p ? t.c : s.c;
        s.d = p ? t.d : s.d; s.u = p ? t.u : s.u; s.v = p ? t.v : s.v;
    }
}

DI M6 ld6(const float* p) { M6 m; m.a=p[0]; m.b=p[1]; m.c=p[2]; m.d=p[3]; m.u=p[4]; m.v=p[5]; return m; }
DI void st6(float* p, const M6& m) { p[0]=m.a; p[1]=m.b; p[2]=m.c; p[3]=m.d; p[4]=m.u; p[5]=m.v; }

DI float fast_tanh(float x) {            // exact at saturation (inf-safe)
    float e = __expf(2.0f * x);
    return 1.0f - 2.0f / (e + 1.0f);
}

DI void stage_frames(const float* __restrict__ logits, int b, int F, int tid,
                     float (*sfa)[2], float (*sfb)[3]) {
    if (tid < NFR) {
        int fidx = F + tid; if (fidx > 127) fidx = 127;
        const float* L = logits + (size_t)(b * NF + fidx) * 5;
        float a1 = 2.0f * tanhf(L[0]) * STAB;
        float aa = fabsf(a1);
        float a2 = ((2.0f - aa) * tanhf(L[1]) * STAB + aa) * 0.5f;
        sfa[tid][0] = a1; sfa[tid][1] = a2;
        sfb[tid][0] = L[2]; sfb[tid][1] = L[3]; sfb[tid][2] = L[4];
    }
}

DI void interp_at(int t, int F, const float (*sfa)[2], const float (*sfb)[3],
                  float& a1, float& a2, float& b0, float& b1, float& b2) {
    float pos = (float)t * CPOS;                 // monotone; floor(pos) >= F
    int i0 = (int)pos;
    int i1 = (i0 + 1 > 127) ? 127 : i0 + 1;
    float fr = pos - (float)i0, w0 = 1.0f - fr;
    int l0 = i0 - F, l1 = i1 - F;
    a1 = sfa[l0][0] * w0 + sfa[l1][0] * fr;
    a2 = sfa[l0][1] * w0 + sfa[l1][1] * fr;
    b0 = sfb[l0][0] * w0 + sfb[l1][0] * fr;
    b1 = sfb[l0][1] * w0 + sfb[l1][1] * fr;
    b2 = sfb[l0][2] * w0 + sfb[l1][2] * fr;
}

// Block scan over per-thread aggregates; returns EXCLUSIVE prefix for this
// thread; if publish!=nullptr, tid TB-1 stores the block total there.
// Contains one __syncthreads.
DI M6 block_scan_E(M6 A, float (*wt)[6], int tid, float* publish) {
    const int lane = tid & 63, w = tid >> 6;
    wave_scan6<64>(A, lane);
    if (lane == 63) st6(wt[w], A);
    __syncthreads();
    M6 P; P.a = 1.f; P.b = 0.f; P.c = 0.f; P.d = 1.f; P.u = 0.f; P.v = 0.f;
    for (int i = 0; i < w; i++) P = comp(ld6(wt[i]), P);
    if (publish && tid == TB - 1) st6(publish, comp(A, P));
    M6 prev;
    prev.a = __shfl_up(A.a, 1, 64); prev.b = __shfl_up(A.b, 1, 64);
    prev.c = __shfl_up(A.c, 1, 64); prev.d = __shfl_up(A.d, 1, 64);
    prev.u = __shfl_up(A.u, 1, 64); prev.v = __shfl_up(A.v, 1, 64);
    return (lane == 0) ? P : comp(prev, P);
}

// wave 0 scans this batch's NC chunk summaries into sv (state after chunk i).
DI void cross_scan(const float* __restrict__ ws_chunk, int b, int tid,
                   float (*sv)[2]) {
    if (tid < 64) {
        M6 cs;
        if (tid < NC) cs = ld6(ws_chunk + ((size_t)b * NC + tid) * 6);
        else { cs.a = 1.f; cs.b = 0.f; cs.c = 0.f; cs.d = 1.f; cs.u = 0.f; cs.v = 0.f; }
        wave_scan6<NC>(cs, tid);
        if (tid < NC) { sv[tid][0] = cs.u; sv[tid][1] = cs.v; }
    }
}

// ---------------- K1: osc + env + coeff planes + chunk summary ---------------
__global__ __launch_bounds__(TB) void k_osc(
    const float* __restrict__ f0_hz, const float* __restrict__ note_dur,
    const float* __restrict__ phase, const float* __restrict__ logits,
    const float* __restrict__ osc_shape, const float* __restrict__ osc_gain,
    const float* __restrict__ alpha,
    float* __restrict__ ws_chunk, float* __restrict__ out) {
    __shared__ float sfa[NFR][2], sfb[NFR][3], wt[4][6];
    const int bid = blockIdx.x, b = bid / NC, c = bid % NC, tid = threadIdx.x;
    const int t0 = c * SAMP + tid * S;
    const size_t g0 = (size_t)b * NS + t0;
    const int F = (int)((float)(c * SAMP) * CPOS);

    stage_frames(logits, b, F, tid, sfa, sfb);

    const float f0 = f0_hz[b], ph = phase[b], sh = osc_shape[b];
    const float gn = osc_gain[b], dur = note_dur[b], al = alpha[b];
    const double inc = (double)f0 / 48000.0;
    const float partials = 12000.0f / (f0 * __log10f(f0));
    const double cum0 = (double)(t0 + 1) * inc;
    const double uu0 = cum0 - 2.0 * floor(cum0 * 0.5);            // mod 2
    const float theta0 = (float)(PI_D * uu0 + 0.5 * (double)ph);  // arg/2
    const float dth = (float)(PI_D * inc);

    __syncthreads();   // frame staging visible

    M6 A;
    #pragma unroll
    for (int h = 0; h < S / G; h++) {
        float xv[G], ev[G], a1s[G], a2s[G], b0s[G], b1s[G], b2s[G];
        #pragma unroll
        for (int k = 0; k < G; k++) {
            int idx = h * G + k, t = t0 + idx;
            float theta = theta0 + (float)idx * dth;
            float sn, cs;
            __sincosf(theta, &sn, &cs);
            float sq = fast_tanh(1.57079632679f * partials * (2.0f * sn * cs));
            float dry0 = (1.0f - 0.5f * sh) * sq * (1.0f + sh * cs);
            float tsec = (float)t * (1.0f / 48000.0f);
            float env = 0.0f;
            if (tsec <= dur) {
                float ramp = 1.0f - tsec / dur;
                ramp = ramp < 0.001f ? 0.001f : (ramp > 1.0f ? 1.0f : ramp);
                env = __expf(al * __logf(ramp));
            }
            ev[k] = env;
            float x = dry0 * gn * env;
            xv[k] = x;
            float a1, a2, b0, b1, b2;
            interp_at(t, F, sfa, sfb, a1, a2, b0, b1, b2);
            a1s[k] = a1; a2s[k] = a2; b0s[k] = b0; b1s[k] = b1; b2s[k] = b2;
            if (idx == 0) { A.a = -a1; A.b = -a2; A.c = 1.f; A.d = 0.f; A.u = x; A.v = 0.f; }
            else stepL(A, a1, a2, x);
        }
        const size_t gh = g0 + h * G;
        *(float4*)&out[gh]         = make_float4(xv[0], xv[1], xv[2], xv[3]);     // dry
        *(float4*)&out[2 * U + gh] = make_float4(ev[0], ev[1], ev[2], ev[3]);     // env
        float* a3 = out + 4 * U + gh * 3;
        *(float4*)&a3[0] = make_float4(1.0f, a1s[0], a2s[0], 1.0f);
        *(float4*)&a3[4] = make_float4(a1s[1], a2s[1], 1.0f, a1s[2]);
        *(float4*)&a3[8] = make_float4(a2s[2], 1.0f, a1s[3], a2s[3]);
        float* bc = out + 7 * U + gh * 3;
        *(float4*)&bc[0] = make_float4(b0s[0], b1s[0], b2s[0], b0s[1]);
        *(float4*)&bc[4] = make_float4(b1s[1], b2s[1], b0s[2], b1s[2]);
        *(float4*)&bc[8] = make_float4(b2s[2], b0s[3], b1s[3], b2s[3]);
    }
    (void)block_scan_E(A, wt, tid, ws_chunk + ((size_t)b * NC + c) * 6);
}

// ---------------- K2: cross-chunk prefix + in-chunk scan + FIR + tanh --------
__global__ __launch_bounds__(TB) void k_iir(
    const float* __restrict__ logits, const float* __restrict__ dist_gain,
    const float* __restrict__ ws_chunk, float* __restrict__ out) {
    __shared__ float sfa[NFR][2], sfb[NFR][3], wt[4][6], sv[NC][2];
    const int bid = blockIdx.x, b = bid / NC, c = bid % NC, tid = threadIdx.x;
    const int t0 = c * SAMP + tid * S;
    const size_t g0 = (size_t)b * NS + t0;
    const int F = (int)((float)(c * SAMP) * CPOS);

    stage_frames(logits, b, F, tid, sfa, sfb);
    cross_scan(ws_chunk, b, tid, sv);

    float x[S];
    {
        float4 v0 = *(const float4*)&out[g0];       // dry plane (k_osc output)
        float4 v1 = *(const float4*)&out[g0 + 4];
        x[0]=v0.x; x[1]=v0.y; x[2]=v0.z; x[3]=v0.w;
        x[4]=v1.x; x[5]=v1.y; x[6]=v1.z; x[7]=v1.w;
    }
    __syncthreads();   // staging + sv visible

    float a1v[S], a2v[S], b0v[S], b1v[S], b2v[S];
    M6 A;
    #pragma unroll
    for (int k = 0; k < S; k++) {
        interp_at(t0 + k, F, sfa, sfb, a1v[k], a2v[k], b0v[k], b1v[k], b2v[k]);
        if (k == 0) { A.a = -a1v[0]; A.b = -a2v[0]; A.c = 1.f; A.d = 0.f; A.u = x[0]; A.v = 0.f; }
        else stepL(A, a1v[k], a2v[k], x[k]);
    }
    M6 E = block_scan_E(A, wt, tid, nullptr);       // one barrier inside
    const float s0 = c ? sv[c - 1][0] : 0.0f;       // y[-1] entering this chunk
    const float s1 = c ? sv[c - 1][1] : 0.0f;       // y[-2]

    float y1 = fmaf(E.a, s0, fmaf(E.b, s1, E.u));   // y[t0-1]
    float y2 = fmaf(E.c, s0, fmaf(E.d, s1, E.v));   // y[t0-2]
    const float dg = dist_gain[b];

    float yv[S], yabv[S], wetv[S];
    #pragma unroll
    for (int k = 0; k < S; k++) {
        float yn = fmaf(-a1v[k], y1, fmaf(-a2v[k], y2, x[k]));
        float yab = b0v[k] * yn + b1v[k] * y1 + b2v[k] * y2;
        yv[k] = yn; yabv[k] = yab; wetv[k] = fast_tanh(yab * dg);
        y2 = y1; y1 = yn;
    }

    *(float4*)&out[U + g0]          = make_float4(wetv[0], wetv[1], wetv[2], wetv[3]);
    *(float4*)&out[U + g0 + 4]      = make_float4(wetv[4], wetv[5], wetv[6], wetv[7]);
    *(float4*)&out[3 * U + g0]      = make_float4(yabv[0], yabv[1], yabv[2], yabv[3]);
    *(float4*)&out[3 * U + g0 + 4]  = make_float4(yabv[4], yabv[5], yabv[6], yabv[7]);
    *(float4*)&out[10 * U + g0]     = make_float4(yv[0], yv[1], yv[2], yv[3]);
    *(float4*)&out[10 * U + g0 + 4] = make_float4(yv[4], yv[5], yv[6], yv[7]);
}

extern "C" void kernel_launch(void* const* d_in, const int* in_sizes, int n_in,
                              void* d_out, int out_size, void* d_ws, size_t ws_size,
                              hipStream_t stream) {
    const float* f0   = (const float*)d_in[0];
    const float* dur  = (const float*)d_in[1];
    const float* ph   = (const float*)d_in[2];
    const float* lg   = (const float*)d_in[3];
    const float* shp  = (const float*)d_in[4];
    const float* gn   = (const float*)d_in[5];
    const float* dist = (const float*)d_in[6];
    const float* alp  = (const float*)d_in[7];
    float* out = (float*)d_out;
    float* ws_chunk = (float*)d_ws;            // GRID*6 f32 = 24 KB

    k_osc<<<GRID, TB, 0, stream>>>(f0, dur, ph, lg, shp, gn, alp, ws_chunk, out);
    k_iir<<<GRID, TB, 0, stream>>>(lg, dist, ws_chunk, out);
}

// Round 9
// 131.184 us; speedup vs baseline: 2.3691x; 1.0752x over previous
//
#include <hip/hip_runtime.h>
#include <cmath>

#define DI __device__ __forceinline__

constexpr int BS = 32;
constexpr int NS = 65536;
constexpr int NF = 128;
constexpr int S  = 4;               // samples per thread (R5 optimum)
constexpr int TB = 256;             // threads per block
constexpr int SAMP = TB * S;        // 1024 samples per chunk
constexpr int NC = NS / SAMP;       // 64 chunks per batch
constexpr size_t U = (size_t)BS * NS;
constexpr double PI_D = 3.14159265358979323846;
constexpr float STAB = 0.999f;

// Affine map on IIR state s=(y[t-1],y[t-2]):  s' = M*s + v.
// M=[[a,b],[c,d]], v=(u,v). One sample: M=[[-a1,-a2],[1,0]], v=(x,0).
struct M6 { float a, b, c, d, u, v; };

DI M6 comp(const M6& R, const M6& L) {   // apply L first, then R
    M6 o;
    o.a = fmaf(R.a, L.a, R.b * L.c);
    o.b = fmaf(R.a, L.b, R.b * L.d);
    o.c = fmaf(R.c, L.a, R.d * L.c);
    o.d = fmaf(R.c, L.b, R.d * L.d);
    o.u = fmaf(R.a, L.u, fmaf(R.b, L.v, R.u));
    o.v = fmaf(R.c, L.u, fmaf(R.d, L.v, R.v));
    return o;
}

// Prepend one companion step (a1,a2,x) on the LEFT (later in time) of A.
DI void stepL(M6& A, float a1, float a2, float x) {
    float na = fmaf(-a1, A.a, -a2 * A.c);
    float nb = fmaf(-a1, A.b, -a2 * A.d);
    float nu = fmaf(-a1, A.u, fmaf(-a2, A.v, x));
    A.c = A.a; A.d = A.b; A.v = A.u;
    A.a = na;  A.b = nb;  A.u = nu;
}

DI void wave_scan6(M6& s, int lane) {    // inclusive, time order = lane order
    #pragma unroll
    for (int d = 1; d < 64; d <<= 1) {
        M6 o;
        o.a = __shfl_up(s.a, d, 64); o.b = __shfl_up(s.b, d, 64);
        o.c = __shfl_up(s.c, d, 64); o.d = __shfl_up(s.d, d, 64);
        o.u = __shfl_up(s.u, d, 64); o.v = __shfl_up(s.v, d, 64);
        M6 t = comp(s, o);
        bool p = lane >= d;
        s.a = p ? t.a : s.a; s.b = p ? t.b : s.b; s.c = p ? t.c : s.c;
        s.d = p ? t.d : s.d; s.u = p ? t.u : s.u; s.v = p ? t.v : s.v;
    }
}

DI M6 ld6(const float* p) { M6 m; m.a=p[0]; m.b=p[1]; m.c=p[2]; m.d=p[3]; m.u=p[4]; m.v=p[5]; return m; }
DI void st6(float* p, const M6& m) { p[0]=m.a; p[1]=m.b; p[2]=m.c; p[3]=m.d; p[4]=m.u; p[5]=m.v; }

// align_corners interp position
DI void ipos(int t, int& i0, int& i1, float& fr) {
    double pos = (double)t * (127.0 / 65535.0);
    int p0 = (int)pos;
    i0 = p0;
    i1 = (p0 + 1 > 127) ? 127 : p0 + 1;
    fr = (float)(pos - (double)p0);
}

DI float fast_tanh(float x) {            // exact at saturation (inf-safe)
    float e = __expf(2.0f * x);
    return 1.0f - 2.0f / (e + 1.0f);
}

// Stage the <=4 frames a 1024-sample chunk touches.
DI void stage_frames(const float* __restrict__ logits, int b, int F, int tid,
                     float (*sfa)[2], float (*sfb)[3]) {
    if (tid < 4) {
        int fidx = F + tid; if (fidx > 127) fidx = 127;
        const float* L = logits + (size_t)(b * NF + fidx) * 5;
        float a1 = 2.0f * tanhf(L[0]) * STAB;
        float aa = fabsf(a1);
        float a2 = ((2.0f - aa) * tanhf(L[1]) * STAB + aa) * 0.5f;
        sfa[tid][0] = a1; sfa[tid][1] = a2;
        sfb[tid][0] = L[2]; sfb[tid][1] = L[3]; sfb[tid][2] = L[4];
    }
}

// Per-sample interp from staged frames (l-indices relative to F).
DI void interp4(int t0, int F, const float (*sfa)[2], const float (*sfb)[3],
                float* a1v, float* a2v, float* b0v, float* b1v, float* b2v) {
    #pragma unroll
    for (int k = 0; k < S; k++) {
        int i0, i1; float fr;
        ipos(t0 + k, i0, i1, fr);
        float w0 = 1.0f - fr;
        int l0 = i0 - F, l1 = i1 - F;
        a1v[k] = sfa[l0][0] * w0 + sfa[l1][0] * fr;
        a2v[k] = sfa[l0][1] * w0 + sfa[l1][1] * fr;
        b0v[k] = sfb[l0][0] * w0 + sfb[l1][0] * fr;
        b1v[k] = sfb[l0][1] * w0 + sfb[l1][1] * fr;
        b2v[k] = sfb[l0][2] * w0 + sfb[l1][2] * fr;
    }
}

// ---------------- K1: osc + env + coeff planes + chunk summary ----------------
__global__ __launch_bounds__(TB) void k_osc(
    const float* __restrict__ f0_hz, const float* __restrict__ note_dur,
    const float* __restrict__ phase, const float* __restrict__ logits,
    const float* __restrict__ osc_shape, const float* __restrict__ osc_gain,
    const float* __restrict__ alpha,
    float* __restrict__ ws_chunk, float* __restrict__ out) {
    __shared__ float sfa[4][2], sfb[4][3], wt[4][6];
    const int bid = blockIdx.x;
    const int b = bid / NC, c = bid % NC;
    const int tid = threadIdx.x;
    const int t0 = c * SAMP + tid * S;
    const size_t g0 = (size_t)b * NS + t0;
    const int F = (int)((double)(c * SAMP) * (127.0 / 65535.0));

    stage_frames(logits, b, F, tid, sfa, sfb);

    const float f0 = f0_hz[b];
    const float ph = phase[b];
    const float sh = osc_shape[b];
    const float gn = osc_gain[b];
    const float dur = note_dur[b];
    const float al = alpha[b];
    const double inc = (double)f0 / 48000.0;
    const float partials = 12000.0f / (f0 * __log10f(f0));

    // one f64 phase reduction per thread; f32 increments within (k<4)
    const double cum0 = (double)(t0 + 1) * inc;
    const double uu0 = cum0 - 2.0 * floor(cum0 * 0.5);            // mod 2
    const float theta0 = (float)(PI_D * uu0 + 0.5 * (double)ph);  // arg/2
    const float dth = (float)(PI_D * inc);

    float x[S], env4[S];
    #pragma unroll
    for (int k = 0; k < S; k++) {
        int t = t0 + k;
        float theta = theta0 + (float)k * dth;
        float sn, cs;
        __sincosf(theta, &sn, &cs);
        float sq = fast_tanh(1.57079632679f * partials * (2.0f * sn * cs));
        float dry0 = (1.0f - 0.5f * sh) * sq * (1.0f + sh * cs);
        float tsec = (float)t * (1.0f / 48000.0f);
        float env = 0.0f;
        if (tsec <= dur) {
            float ramp = 1.0f - tsec / dur;
            ramp = ramp < 0.001f ? 0.001f : (ramp > 1.0f ? 1.0f : ramp);
            env = __expf(al * __logf(ramp));
        }
        env4[k] = env;
        x[k] = dry0 * gn * env;
    }
    __syncthreads();   // frame staging visible

    float a1v[S], a2v[S], b0v[S], b1v[S], b2v[S];
    interp4(t0, F, sfa, sfb, a1v, a2v, b0v, b1v, b2v);

    // --- vectorized stores
    *(float4*)&out[g0]         = make_float4(x[0], x[1], x[2], x[3]);          // dry
    *(float4*)&out[2 * U + g0] = make_float4(env4[0], env4[1], env4[2], env4[3]); // env
    float* a3 = out + 4 * U + g0 * 3;
    *(float4*)&a3[0] = make_float4(1.0f, a1v[0], a2v[0], 1.0f);
    *(float4*)&a3[4] = make_float4(a1v[1], a2v[1], 1.0f, a1v[2]);
    *(float4*)&a3[8] = make_float4(a2v[2], 1.0f, a1v[3], a2v[3]);
    float* bc = out + 7 * U + g0 * 3;
    *(float4*)&bc[0] = make_float4(b0v[0], b1v[0], b2v[0], b0v[1]);
    *(float4*)&bc[4] = make_float4(b1v[1], b2v[1], b0v[2], b1v[2]);
    *(float4*)&bc[8] = make_float4(b2v[2], b0v[3], b1v[3], b2v[3]);

    // --- chunk summary: serial 4-step aggregate, then block scan
    M6 A; A.a = -a1v[0]; A.b = -a2v[0]; A.c = 1.0f; A.d = 0.0f; A.u = x[0]; A.v = 0.0f;
    #pragma unroll
    for (int k = 1; k < S; k++) stepL(A, a1v[k], a2v[k], x[k]);

    const int lane = tid & 63, w = tid >> 6;
    wave_scan6(A, lane);
    if (lane == 63) st6(wt[w], A);
    __syncthreads();
    if (tid == TB - 1) {
        M6 p = ld6(wt[0]);
        p = comp(ld6(wt[1]), p);
        p = comp(ld6(wt[2]), p);
        M6 tot = comp(A, p);
        st6(ws_chunk + ((size_t)b * NC + c) * 6, tot);
    }
}

// ---------------- K2: cross-chunk prefix + in-chunk scan + FIR + tanh ---------
__global__ __launch_bounds__(TB) void k_iir(
    const float* __restrict__ logits, const float* __restrict__ dist_gain,
    const float* __restrict__ ws_chunk, float* __restrict__ out) {
    __shared__ float sfa[4][2], sfb[4][3], wt[4][6], sv[NC][2];
    const int bid = blockIdx.x;
    const int b = bid / NC, c = bid % NC;
    const int tid = threadIdx.x;
    const int t0 = c * SAMP + tid * S;
    const size_t g0 = (size_t)b * NS + t0;
    const int F = (int)((double)(c * SAMP) * (127.0 / 65535.0));

    stage_frames(logits, b, F, tid, sfa, sfb);

    // phase A: wave 0 scans this batch's 64 chunk summaries
    if (tid < NC) {
        M6 cs = ld6(ws_chunk + ((size_t)b * NC + tid) * 6);
        wave_scan6(cs, tid);
        sv[tid][0] = cs.u; sv[tid][1] = cs.v;   // state after chunk tid (zero init)
    }

    float4 xv = *(const float4*)&out[g0];       // dry (plane 0)
    float x[S] = {xv.x, xv.y, xv.z, xv.w};

    __syncthreads();
    const float s0 = c ? sv[c - 1][0] : 0.0f;   // y[-1] entering this chunk
    const float s1 = c ? sv[c - 1][1] : 0.0f;   // y[-2]

    float a1v[S], a2v[S], b0v[S], b1v[S], b2v[S];
    interp4(t0, F, sfa, sfb, a1v, a2v, b0v, b1v, b2v);

    // per-thread 4-step aggregate + inclusive block scan
    M6 A; A.a = -a1v[0]; A.b = -a2v[0]; A.c = 1.0f; A.d = 0.0f; A.u = x[0]; A.v = 0.0f;
    #pragma unroll
    for (int k = 1; k < S; k++) stepL(A, a1v[k], a2v[k], x[k]);

    const int lane = tid & 63, w = tid >> 6;
    wave_scan6(A, lane);
    if (lane == 63) st6(wt[w], A);
    __syncthreads();

    M6 P; P.a = 1.f; P.b = 0.f; P.c = 0.f; P.d = 1.f; P.u = 0.f; P.v = 0.f;
    for (int i = 0; i < w; i++) P = comp(ld6(wt[i]), P);
    M6 prev;
    prev.a = __shfl_up(A.a, 1, 64); prev.b = __shfl_up(A.b, 1, 64);
    prev.c = __shfl_up(A.c, 1, 64); prev.d = __shfl_up(A.d, 1, 64);
    prev.u = __shfl_up(A.u, 1, 64); prev.v = __shfl_up(A.v, 1, 64);
    M6 E = (lane == 0) ? P : comp(prev, P);     // aggregate of samples before this thread

    // state entering this thread's 4 samples
    float y1 = fmaf(E.a, s0, fmaf(E.b, s1, E.u));
    float y2 = fmaf(E.c, s0, fmaf(E.d, s1, E.v));
    const float ys0 = y1, ys1 = y2;

    float y[S];
    #pragma unroll
    for (int k = 0; k < S; k++) {
        y[k] = fmaf(-a1v[k], y1, fmaf(-a2v[k], y2, x[k]));
        y2 = y1; y1 = y[k];
    }

    const float dg = dist_gain[b];
    float yab[S], wet[S];
    #pragma unroll
    for (int k = 0; k < S; k++) {
        float ym1 = (k >= 1) ? y[k - 1] : ys0;
        float ym2 = (k >= 2) ? y[k - 2] : ((k == 1) ? ys0 : ys1);
        yab[k] = b0v[k] * y[k] + b1v[k] * ym1 + b2v[k] * ym2;
        wet[k] = fast_tanh(yab[k] * dg);
    }

    *(float4*)&out[U + g0]      = make_float4(wet[0], wet[1], wet[2], wet[3]);
    *(float4*)&out[3 * U + g0]  = make_float4(yab[0], yab[1], yab[2], yab[3]);
    *(float4*)&out[10 * U + g0] = make_float4(y[0], y[1], y[2], y[3]);
}

extern "C" void kernel_launch(void* const* d_in, const int* in_sizes, int n_in,
                              void* d_out, int out_size, void* d_ws, size_t ws_size,
                              hipStream_t stream) {
    const float* f0   = (const float*)d_in[0];
    const float* dur  = (const float*)d_in[1];
    const float* ph   = (const float*)d_in[2];
    const float* lg   = (const float*)d_in[3];
    const float* shp  = (const float*)d_in[4];
    const float* gn   = (const float*)d_in[5];
    const float* dist = (const float*)d_in[6];
    const float* alp  = (const float*)d_in[7];
    float* out = (float*)d_out;
    float* ws_chunk = (float*)d_ws;            // BS*NC*6 f32 = 48 KB

    k_osc<<<BS * NC, TB, 0, stream>>>(f0, dur, ph, lg, shp, gn, alp, ws_chunk, out);
    k_iir<<<BS * NC, TB, 0, stream>>>(lg, dist, ws_chunk, out);
}